// Round 12
// baseline (551.304 us; speedup 1.0000x reference)
//
#include <hip/hip_runtime.h>
#include <cstdint>
#include <cstddef>

#define SEQL   2048
#define DMODEL 1024
#define NHEADS 16
#define DHEAD  64
#define MROWS  4096   // BATCH * SEQ

typedef __attribute__((ext_vector_type(8))) short short8;   // 8 bf16 (4 VGPRs)
typedef __attribute__((ext_vector_type(4))) float f32x4;    // MFMA 16x16 C/D

__device__ __forceinline__ unsigned short f2bf(float x) {
  unsigned int u = __float_as_uint(x);
  u += 0x7fffu + ((u >> 16) & 1u);   // round-to-nearest-even
  return (unsigned short)(u >> 16);
}
__device__ __forceinline__ float bf2f(unsigned short u) {
  return __uint_as_float(((unsigned int)u) << 16);
}
// load 8 contiguous fp32, round to 8 bf16
__device__ __forceinline__ short8 cvt8(const float* __restrict__ p) {
  const float4 lo = *(const float4*)p;
  const float4 hi = *(const float4*)(p + 4);
  short8 v;
  v[0] = (short)f2bf(lo.x); v[1] = (short)f2bf(lo.y);
  v[2] = (short)f2bf(lo.z); v[3] = (short)f2bf(lo.w);
  v[4] = (short)f2bf(hi.x); v[5] = (short)f2bf(hi.y);
  v[6] = (short)f2bf(hi.z); v[7] = (short)f2bf(hi.w);
  return v;
}
// async global->LDS, 16B per lane; lds base must be wave-uniform
__device__ __forceinline__ void gload_lds16(const unsigned short* g, unsigned short* l) {
  __builtin_amdgcn_global_load_lds(
      (const __attribute__((address_space(1))) unsigned int*)g,
      (__attribute__((address_space(3))) unsigned int*)l, 16, 0, 0);
}

// ---------------------------------------------------------------------------
// One-shot fp32 -> bf16 conversion of x and the four weight matrices.
// ---------------------------------------------------------------------------
__global__ __launch_bounds__(256) void cvt_bf16(
    const float* __restrict__ x,  const float* __restrict__ wq,
    const float* __restrict__ wk, const float* __restrict__ wv,
    const float* __restrict__ wo,
    unsigned short* __restrict__ xb,  unsigned short* __restrict__ wqb,
    unsigned short* __restrict__ wkb, unsigned short* __restrict__ wvb,
    unsigned short* __restrict__ wob) {
  const int y = blockIdx.y;
  const float* src; unsigned short* dst;
  if (y < 4)       { src = x + ((size_t)y << 20); dst = xb + ((size_t)y << 20); }
  else if (y == 4) { src = wq; dst = wqb; }
  else if (y == 5) { src = wk; dst = wkb; }
  else if (y == 6) { src = wv; dst = wvb; }
  else             { src = wo; dst = wob; }
  const size_t i = ((size_t)blockIdx.x * 256 + threadIdx.x) * 8;
  *(short8*)(dst + i) = cvt8(src + i);
}

// ---------------------------------------------------------------------------
// QKV projection, all-bf16, async staging + FUSED ROPE epilogue (R12).
// z=0 -> Q bf16 (roped, x0.125); z=1 -> K bf16 (roped); z=2 -> V transposed.
// RoPE in C/D layout: pair (2i,2i+1) sits on adjacent lanes (col=..+l15), so
// partner value = shfl_xor(acc,1); even lane: e*cos-o*sin, odd: e*sin+o*cos.
// ---------------------------------------------------------------------------
__global__ __launch_bounds__(256) void gemm_qkv(
    const unsigned short* __restrict__ A,
    const unsigned short* __restrict__ W0, const unsigned short* __restrict__ W1,
    const unsigned short* __restrict__ W2,
    unsigned short* __restrict__ C0, unsigned short* __restrict__ C1,
    unsigned short* __restrict__ Vt,
    const int* __restrict__ tpos,
    int Mda, int Nda, int Kda) {
  const unsigned short* W;
  if (blockIdx.z == 0)      W = W0;
  else if (blockIdx.z == 1) W = W1;
  else                      W = W2;

  __shared__ __attribute__((aligned(16))) unsigned short As[128 * 32];
  __shared__ __attribute__((aligned(16))) unsigned short Bs[128 * 32];

  const int t = threadIdx.x;
  const int m0 = blockIdx.y * 128, n0 = blockIdx.x * 128;
  const int w = t >> 6, lane = t & 63;
  const int l15 = lane & 15, quad = lane >> 4;
  const int wm = (w >> 1) * 64, wn = (w & 1) * 64;

  const int r1 = t >> 2,         c1 = (t & 3) * 8;
  const int r2 = (t + 256) >> 2, c2 = (t & 3) * 8;
  unsigned short* asd1 = As + (size_t)(w << 6) * 8;
  unsigned short* asd2 = As + (size_t)(256 + (w << 6)) * 8;
  unsigned short* bsd1 = Bs + (size_t)(w << 6) * 8;
  unsigned short* bsd2 = Bs + (size_t)(256 + (w << 6)) * 8;

  f32x4 acc[4][4] = {};

  for (int k0 = 0; k0 < Kda; k0 += 32) {
    __syncthreads();
    gload_lds16(A + (size_t)(m0 + r1) * Kda + k0 + c1, asd1);
    gload_lds16(A + (size_t)(m0 + r2) * Kda + k0 + c2, asd2);
    gload_lds16(W + (size_t)(n0 + r1) * Kda + k0 + c1, bsd1);
    gload_lds16(W + (size_t)(n0 + r2) * Kda + k0 + c2, bsd2);
    __syncthreads();

    short8 af[4], bfr[4];
#pragma unroll
    for (int i = 0; i < 4; ++i)
      af[i] = *(const short8*)(&As[(wm + i * 16 + l15) * 32 + quad * 8]);
#pragma unroll
    for (int j = 0; j < 4; ++j)
      bfr[j] = *(const short8*)(&Bs[(wn + j * 16 + l15) * 32 + quad * 8]);
#pragma unroll
    for (int i = 0; i < 4; ++i)
#pragma unroll
      for (int j = 0; j < 4; ++j)
        acc[i][j] = __builtin_amdgcn_mfma_f32_16x16x32_bf16(af[i], bfr[j], acc[i][j], 0, 0, 0);
  }

  if (blockIdx.z != 2) {
    // fused RoPE epilogue for Q (z=0, scaled 0.125) and K (z=1)
    unsigned short* C = (blockIdx.z == 0) ? C0 : C1;
    const float qscale = (blockIdx.z == 0) ? 0.125f : 1.0f;
    const int par = l15 & 1;
    float invf[4];
#pragma unroll
    for (int j = 0; j < 4; ++j) {
      const int d2 = ((wn + j * 16 + l15) & 63) >> 1;   // freq index
      invf[j] = exp2f((float)d2 * -0.4152410118609203f);  // log2(1e4)/32
    }
#pragma unroll
    for (int i = 0; i < 4; ++i)
#pragma unroll
      for (int r = 0; r < 4; ++r) {
        const int row = m0 + wm + i * 16 + quad * 4 + r;
        const float pos = (float)tpos[row & (SEQL - 1)];
#pragma unroll
        for (int j = 0; j < 4; ++j) {
          float sn, cs;
          sincosf(pos * invf[j], &sn, &cs);
          const float own = acc[i][j][r];
          const float part = __shfl_xor(own, 1);
          const float v = (par == 0) ? own * cs - part * sn
                                     : part * sn + own * cs;
          const int col = n0 + wn + j * 16 + l15;
          C[(size_t)row * Nda + col] = f2bf(v * qscale);
        }
      }
  } else {
    // V transposed write: 4 consecutive s-values per 8B store
#pragma unroll
    for (int i = 0; i < 4; ++i) {
      const int srow = m0 + wm + i * 16 + quad * 4;   // b*SEQL + s (s%4==0)
      const int bq = srow >> 11, s = srow & (SEQL - 1);
#pragma unroll
      for (int j = 0; j < 4; ++j) {
        const int col = n0 + wn + j * 16 + l15;       // h*64 + d
        ushort4 v;
        v.x = f2bf(acc[i][j][0]); v.y = f2bf(acc[i][j][1]);
        v.z = f2bf(acc[i][j][2]); v.w = f2bf(acc[i][j][3]);
        *(ushort4*)(Vt + ((size_t)(bq * DMODEL + col)) * SEQL + s) = v;
      }
    }
  }
}

// ---------------------------------------------------------------------------
// Output projection: A bf16 [M][K], W bf16 [N][K], C fp32 [M][N]
// ---------------------------------------------------------------------------
__global__ __launch_bounds__(256) void gemm_out(
    const unsigned short* __restrict__ A,
    const unsigned short* __restrict__ W,
    float* __restrict__ C,
    int Mda, int Nda, int Kda) {
  __shared__ __attribute__((aligned(16))) unsigned short As[128 * 32];
  __shared__ __attribute__((aligned(16))) unsigned short Bs[128 * 32];

  const int t = threadIdx.x;
  const int m0 = blockIdx.y * 128, n0 = blockIdx.x * 128;
  const int w = t >> 6, lane = t & 63;
  const int l15 = lane & 15, quad = lane >> 4;
  const int wm = (w >> 1) * 64, wn = (w & 1) * 64;

  const int r1 = t >> 2,         c1 = (t & 3) * 8;
  const int r2 = (t + 256) >> 2, c2 = (t & 3) * 8;
  unsigned short* asd1 = As + (size_t)(w << 6) * 8;
  unsigned short* asd2 = As + (size_t)(256 + (w << 6)) * 8;
  unsigned short* bsd1 = Bs + (size_t)(w << 6) * 8;
  unsigned short* bsd2 = Bs + (size_t)(256 + (w << 6)) * 8;

  f32x4 acc[4][4] = {};

  for (int k0 = 0; k0 < Kda; k0 += 32) {
    __syncthreads();
    gload_lds16(A + (size_t)(m0 + r1) * Kda + k0 + c1, asd1);
    gload_lds16(A + (size_t)(m0 + r2) * Kda + k0 + c2, asd2);
    gload_lds16(W + (size_t)(n0 + r1) * Kda + k0 + c1, bsd1);
    gload_lds16(W + (size_t)(n0 + r2) * Kda + k0 + c2, bsd2);
    __syncthreads();

    short8 af[4], bfr[4];
#pragma unroll
    for (int i = 0; i < 4; ++i)
      af[i] = *(const short8*)(&As[(wm + i * 16 + l15) * 32 + quad * 8]);
#pragma unroll
    for (int j = 0; j < 4; ++j)
      bfr[j] = *(const short8*)(&Bs[(wn + j * 16 + l15) * 32 + quad * 8]);
#pragma unroll
    for (int i = 0; i < 4; ++i)
#pragma unroll
      for (int j = 0; j < 4; ++j)
        acc[i][j] = __builtin_amdgcn_mfma_f32_16x16x32_bf16(af[i], bfr[j], acc[i][j], 0, 0, 0);
  }

#pragma unroll
  for (int i = 0; i < 4; ++i)
#pragma unroll
    for (int j = 0; j < 4; ++j)
#pragma unroll
      for (int r = 0; r < 4; ++r) {
        int row = m0 + wm + i * 16 + quad * 4 + r;
        int col = n0 + wn + j * 16 + l15;
        C[(size_t)row * Nda + col] = acc[i][j][r];
      }
}

// ---------------------------------------------------------------------------
// Causal attention, R5-verified transposed-MFMA math, 2-barrier DMA staging,
// R12: kv-tile 128 (32 KB LDS/trip, 32 MFMA/wave/trip) = 4 chunks of the
// R11-verified 32-kv pattern. Uniform 17 trips/block via (p, 31-p) pairing.
// Wave-uniform fast path for fully-unmasked trips.
// ---------------------------------------------------------------------------
__global__ __launch_bounds__(256, 2) void attn_kernel(const unsigned short* __restrict__ Kf,
                                                      const unsigned short* __restrict__ Vt,
                                                      unsigned short* __restrict__ Qio) {
  __shared__ __attribute__((aligned(16))) unsigned short Ks[8192];  // 16 KB: 4 chunks x 32kv x 64d
  __shared__ __attribute__((aligned(16))) unsigned short Vs[8192];  // 16 KB

  const int id = blockIdx.x;                    // id = grp*128 + qpair*8 + xcd
  const int bh = ((id >> 7) << 3) | (id & 7);   // grp*8 + xcd (L2 locality)
  const int qpair = (id >> 3) & 15;             // 0..15
  const int b = bh >> 4, h = bh & 15;
  const int w = threadIdx.x >> 6;
  const int lane = threadIdx.x & 63;
  const int l15 = lane & 15, quad = lane >> 4;

  // staging source addresses (lane-permuted so LDS slot = fragment layout)
  const int g = (w << 6) | lane;
  const int ktau = g >> 7, kseg = (g >> 4) & 7, km = g & 15;
  const int kvl = 8 * (km >> 2) + (km & 3) + 4 * ktau;
  const unsigned short* kstage = Kf + ((size_t)(b * SEQL + kvl)) * DMODEL + h * DHEAD + kseg * 8;
  const int vdb = (g >> 6) & 3, vq = (g >> 4) & 3, vm = g & 15;
  const unsigned short* vstage = Vt + ((size_t)(bh * DHEAD + vdb * 16 + vm)) * SEQL + vq * 8;
  const int woff = (w << 6) * 8;   // wave's slot window within a 2048-short chunk

  // fragment read offset (shorts) within a chunk
  const int rs = (l15 + (quad << 4)) << 3;

#pragma unroll 1
  for (int phase = 0; phase < 2; ++phase) {
    const int qblk = (phase == 0) ? qpair : 31 - qpair;
    const int qw = qblk * 64 + w * 16;
    const int qrow = qw + l15;

    // Q B-frag: n=l15 (q), k=8*quad+j (d)
    const unsigned short* qp = Qio + ((size_t)(b * SEQL + qrow)) * DMODEL + h * DHEAD + quad * 8;
    const short8 bq0 = *(const short8*)(qp);
    const short8 bq1 = *(const short8*)(qp + 32);

    f32x4 oa0 = {0.f, 0.f, 0.f, 0.f}, oa1 = oa0, oa2 = oa0, oa3 = oa0;
    float lp = 0.f;

    const int trips = (qblk + 2) >> 1;   // kv128 tiles; block-uniform
    for (int t = 0; t < trips; ++t) {
      const int kv0 = t * 128;
      __syncthreads();   // all waves done reading previous tile
#pragma unroll
      for (int c = 0; c < 4; ++c) {
        gload_lds16(kstage + (size_t)(kv0 + 32 * c) * DMODEL, Ks + c * 2048 + woff);
        gload_lds16(vstage + kv0 + 32 * c, Vs + c * 2048 + woff);
      }
      __syncthreads();   // staged data visible

      const bool full = (kv0 + 127 <= qw);   // wave-uniform
#pragma unroll
      for (int c = 0; c < 4; ++c) {
        const int co = c * 2048;
        const short8 aka0 = *(const short8*)(Ks + co + rs);
        const short8 aka1 = *(const short8*)(Ks + co + rs + 512);
        const short8 akb0 = *(const short8*)(Ks + co + rs + 1024);
        const short8 akb1 = *(const short8*)(Ks + co + rs + 1536);
        f32x4 z = {0.f, 0.f, 0.f, 0.f};
        f32x4 sa = __builtin_amdgcn_mfma_f32_16x16x32_bf16(aka0, bq0, z, 0, 0, 0);
        sa = __builtin_amdgcn_mfma_f32_16x16x32_bf16(aka1, bq1, sa, 0, 0, 0);
        f32x4 sb = __builtin_amdgcn_mfma_f32_16x16x32_bf16(akb0, bq0, z, 0, 0, 0);
        sb = __builtin_amdgcn_mfma_f32_16x16x32_bf16(akb1, bq1, sb, 0, 0, 0);

        short8 bp;
        if (full) {
#pragma unroll
          for (int r = 0; r < 4; ++r) {
            const float pa = __expf(sa[r]);
            const float pb = __expf(sb[r]);
            lp += pa + pb;
            bp[r]     = (short)f2bf(pa);
            bp[4 + r] = (short)f2bf(pb);
          }
        } else {
#pragma unroll
          for (int r = 0; r < 4; ++r) {
            const int kv1 = kv0 + 32 * c + 8 * quad + r;
            const float pa = (kv1 > qrow)     ? 0.f : __expf(sa[r]);
            const float pb = (kv1 + 4 > qrow) ? 0.f : __expf(sb[r]);
            lp += pa + pb;
            bp[r]     = (short)f2bf(pa);
            bp[4 + r] = (short)f2bf(pb);
          }
        }

        const short8 av0 = *(const short8*)(Vs + co + rs);
        const short8 av1 = *(const short8*)(Vs + co + rs + 512);
        const short8 av2 = *(const short8*)(Vs + co + rs + 1024);
        const short8 av3 = *(const short8*)(Vs + co + rs + 1536);
        oa0 = __builtin_amdgcn_mfma_f32_16x16x32_bf16(av0, bp, oa0, 0, 0, 0);
        oa1 = __builtin_amdgcn_mfma_f32_16x16x32_bf16(av1, bp, oa1, 0, 0, 0);
        oa2 = __builtin_amdgcn_mfma_f32_16x16x32_bf16(av2, bp, oa2, 0, 0, 0);
        oa3 = __builtin_amdgcn_mfma_f32_16x16x32_bf16(av3, bp, oa3, 0, 0, 0);
      }
    }

    // reduce row sum across the 4 quads holding this q's kv slices
    lp += __shfl_xor(lp, 16);
    lp += __shfl_xor(lp, 32);
    const float il = 1.f / lp;

    // O^T: lane holds q=l15's d = db*16 + 4*quad + r  -> 4x ushort4 stores
    unsigned short* ob = Qio + ((size_t)(b * SEQL + qrow)) * DMODEL + h * DHEAD + quad * 4;
    {
      ushort4 v;
      v.x = f2bf(oa0[0] * il); v.y = f2bf(oa0[1] * il);
      v.z = f2bf(oa0[2] * il); v.w = f2bf(oa0[3] * il);
      *(ushort4*)(ob) = v;
      v.x = f2bf(oa1[0] * il); v.y = f2bf(oa1[1] * il);
      v.z = f2bf(oa1[2] * il); v.w = f2bf(oa1[3] * il);
      *(ushort4*)(ob + 16) = v;
      v.x = f2bf(oa2[0] * il); v.y = f2bf(oa2[1] * il);
      v.z = f2bf(oa2[2] * il); v.w = f2bf(oa2[3] * il);
      *(ushort4*)(ob + 32) = v;
      v.x = f2bf(oa3[0] * il); v.y = f2bf(oa3[1] * il);
      v.z = f2bf(oa3[2] * il); v.w = f2bf(oa3[3] * il);
      *(ushort4*)(ob + 48) = v;
    }
  }
}

// ---------------------------------------------------------------------------
extern "C" void kernel_launch(void* const* d_in, const int* in_sizes, int n_in,
                              void* d_out, int out_size, void* d_ws, size_t ws_size,
                              hipStream_t stream) {
  (void)in_sizes; (void)n_in; (void)out_size; (void)ws_size;
  const float* x  = (const float*)d_in[0];
  const int* tpos = (const int*)d_in[1];
  const float* Wq = (const float*)d_in[2];
  const float* Wk = (const float*)d_in[3];
  const float* Wv = (const float*)d_in[4];
  const float* Wo = (const float*)d_in[5];
  float* out      = (float*)d_out;

  char* ws = (char*)d_ws;
  const size_t MB = 1024 * 1024;
  unsigned short* Qf  = (unsigned short*)(ws);            // 8 MB
  unsigned short* Kf  = (unsigned short*)(ws + 8 * MB);   // 8 MB
  unsigned short* Vt  = (unsigned short*)(ws + 16 * MB);  // 8 MB
  unsigned short* xb  = (unsigned short*)(ws + 24 * MB);  // 8 MB
  unsigned short* wqb = (unsigned short*)(ws + 32 * MB);  // 2 MB
  unsigned short* wkb = (unsigned short*)(ws + 34 * MB);  // 2 MB
  unsigned short* wvb = (unsigned short*)(ws + 36 * MB);  // 2 MB
  unsigned short* wob = (unsigned short*)(ws + 38 * MB);  // 2 MB -> 40 MB total

  // one-shot fp32 -> bf16 conversion (x + 4 weights)
  cvt_bf16<<<dim3(512, 8), 256, 0, stream>>>(x, Wq, Wk, Wv, Wo, xb, wqb, wkb, wvb, wob);
  // Q,K,V projections with fused RoPE (Q scaled 0.125); V written transposed
  gemm_qkv<<<dim3(8, 32, 3), 256, 0, stream>>>(xb, wqb, wkb, wvb, Qf, Kf, Vt, tpos, MROWS, DMODEL, DMODEL);
  // causal attention; 512 paired blocks (uniform 17 kv128-trips), XCD-swizzled
  attn_kernel<<<dim3(512), 256, 0, stream>>>(Kf, Vt, Qf);
  // output projection (bf16 A, bf16 W, fp32 out)
  gemm_out<<<dim3(8, 32, 1), 256, 0, stream>>>(Qf, wob, out, MROWS, DMODEL, DMODEL);
}